// Round 1
// baseline (83069.250 us; speedup 1.0000x reference)
//
#include <hip/hip_runtime.h>
#include <stdint.h>

#define BB 64
#define TT 512
#define II 512
#define HH 1024
#define OO 512
#define KD 1536      // II + HH
#define KC 256       // k-chunk staged in LDS
#define NCH 6        // KD / KC
#define NBLK 256
#define NTHR 256

// workspace layout (floats)
#define WS_HBUF 256                       // [2][BB][HH] h double buffer
#define WS_NFLOATS (WS_HBUF + 2 * BB * HH)

// LDS layout (floats): two KCxBB chunk buffers + y partial buffer
#define L_COMB0 0
#define L_COMB1 (KC * BB)                 // 16384
#define L_YBUF  (2 * KC * BB)             // 32768
#define L_NFLOATS (L_YBUF + 4 * BB)       // 33024 floats = 132096 B

__device__ __forceinline__ float sigm(float v) {
  return 1.0f / (1.0f + __expf(-v));
}
__device__ __forceinline__ float tanh_c(float v) {
  v = fminf(fmaxf(v, -20.0f), 20.0f);
  float e = __expf(-2.0f * v);
  return (1.0f - e) / (1.0f + e);
}

__device__ __forceinline__ void grid_barrier(uint32_t* cnt, uint32_t target) {
  __builtin_amdgcn_fence(__ATOMIC_RELEASE, "agent");
  __syncthreads();
  if (threadIdx.x == 0) {
    __hip_atomic_fetch_add(cnt, 1u, __ATOMIC_RELEASE, __HIP_MEMORY_SCOPE_AGENT);
    while (__hip_atomic_load(cnt, __ATOMIC_ACQUIRE, __HIP_MEMORY_SCOPE_AGENT) < target) {
      __builtin_amdgcn_s_sleep(2);
    }
  }
  __syncthreads();
  __builtin_amdgcn_fence(__ATOMIC_ACQUIRE, "agent");
}

__global__ void __launch_bounds__(NTHR, 1)
lstm_kernel(const float* __restrict__ x,
            const float* __restrict__ Wf, const float* __restrict__ bf,
            const float* __restrict__ Wi, const float* __restrict__ bi,
            const float* __restrict__ Wc, const float* __restrict__ bc,
            const float* __restrict__ Wo, const float* __restrict__ bo,
            const float* __restrict__ Wfc, const float* __restrict__ bfc,
            float* __restrict__ out, float* __restrict__ ws)
{
  extern __shared__ float lds[];
  const int tid  = threadIdx.x;
  const int blk  = blockIdx.x;
  const int wave = tid >> 6;
  const int lane = tid & 63;
  const int b    = lane;           // batch owned by this lane

  uint32_t* bar = (uint32_t*)ws;
  float* hbuf = ws + WS_HBUF;      // [2][BB][HH]

  // gate work: wave <-> hidden unit
  const int u = __builtin_amdgcn_readfirstlane(blk * 4 + wave);
  const float* rowf = Wf + (size_t)u * KD;
  const float* rowi = Wi + (size_t)u * KD;
  const float* rowc = Wc + (size_t)u * KD;
  const float* rowo = Wo + (size_t)u * KD;
  const float bsf = bf[u], bsi = bi[u], bsc = bc[u], bso = bo[u];

  // y work: wave pair -> output col, wave parity -> k-half
  const int kh = wave & 1;
  const int yq = wave >> 1;
  const int oidx = __builtin_amdgcn_readfirstlane(blk * 2 + yq);
  const float* rowy = Wfc + (size_t)oidx * HH + kh * 512;

  float cstate = 0.0f;             // c[u][b] lives here for the whole run

  for (int it = 0; it <= TT; ++it) {
    const float* hprev = hbuf + (size_t)(it & 1) * (BB * HH);
    float*       hnext = hbuf + (size_t)((it + 1) & 1) * (BB * HH);

    // ---------- y_{it-1} = h_{it-1} @ Wfc^T + bfc (reads hprev) ----------
    if (it > 0) {
      float accy = 0.0f;
      const float* hrow = hprev + (size_t)b * HH + kh * 512;
      #pragma unroll 4
      for (int s = 0; s < 128; ++s) {
        float4 hv = ((const float4*)hrow)[s];
        float4 wv = ((const float4*)rowy)[s];
        accy += hv.x * wv.x + hv.y * wv.y + hv.z * wv.z + hv.w * wv.w;
      }
      lds[L_YBUF + wave * BB + b] = accy;
      __syncthreads();
      if (tid < 2 * BB) {
        int q  = tid >> 6;
        int qb = tid & 63;
        float yv = lds[L_YBUF + (q * 2 + 0) * BB + qb]
                 + lds[L_YBUF + (q * 2 + 1) * BB + qb]
                 + bfc[blk * 2 + q];
        out[(size_t)qb * (TT * OO) + (size_t)(it - 1) * OO + (blk * 2 + q)] = yv;
      }
    }

    if (it < TT) {
      float a0 = 0.f, a1 = 0.f, a2 = 0.f, a3 = 0.f;

      // ---- prologue: stage chunk 0 (pure x) linear-src -> swizzled LDS ----
      {
        float4 v[16];
        #pragma unroll
        for (int i = 0; i < 16; ++i) {
          int bs = i * 4 + wave;
          const float* src = x + (size_t)bs * (TT * II) + (size_t)it * II;
          v[i] = ((const float4*)src)[lane];
        }
        float4* dstb = (float4*)(lds + L_COMB0);
        #pragma unroll
        for (int i = 0; i < 16; ++i) {
          int bs = i * 4 + wave;
          dstb[bs * 64 + (lane ^ (bs & 15))] = v[i];
        }
      }
      __syncthreads();

      // ---- main K loop: double-buffered chunks ----
      for (int kc = 0; kc < NCH; ++kc) {
        float4 v[16];
        if (kc + 1 < NCH) {                      // issue next chunk's loads
          const int k0n = (kc + 1) * KC;
          #pragma unroll
          for (int i = 0; i < 16; ++i) {
            int bs = i * 4 + wave;
            const float* src = (k0n < II)
              ? (x + (size_t)bs * (TT * II) + (size_t)it * II + k0n)
              : (hprev + (size_t)bs * HH + (k0n - II));
            v[i] = ((const float4*)src)[lane];
          }
        }
        {
          const float4* cb = (const float4*)(lds + ((kc & 1) ? L_COMB1 : L_COMB0)) + b * 64;
          const int k0 = kc * KC;
          const int m = b & 15;
          #pragma unroll 4
          for (int s = 0; s < 64; ++s) {
            float4 cv = cb[s ^ m];
            float4 w0 = *(const float4*)(rowf + k0 + 4 * s);
            float4 w1 = *(const float4*)(rowi + k0 + 4 * s);
            float4 w2 = *(const float4*)(rowc + k0 + 4 * s);
            float4 w3 = *(const float4*)(rowo + k0 + 4 * s);
            a0 += cv.x * w0.x + cv.y * w0.y + cv.z * w0.z + cv.w * w0.w;
            a1 += cv.x * w1.x + cv.y * w1.y + cv.z * w1.z + cv.w * w1.w;
            a2 += cv.x * w2.x + cv.y * w2.y + cv.z * w2.z + cv.w * w2.w;
            a3 += cv.x * w3.x + cv.y * w3.y + cv.z * w3.z + cv.w * w3.w;
          }
        }
        if (kc + 1 < NCH) {                      // write staged regs, swap
          float4* dstb = (float4*)(lds + (((kc + 1) & 1) ? L_COMB1 : L_COMB0));
          #pragma unroll
          for (int i = 0; i < 16; ++i) {
            int bs = i * 4 + wave;
            dstb[bs * 64 + (lane ^ (bs & 15))] = v[i];
          }
          __syncthreads();
        }
      }

      // ---- elementwise update: c,h for (u, b) ----
      float gf = sigm(a0 + bsf);
      float gi = sigm(a1 + bsi);
      float gc = tanh_c(a2 + bsc);
      float go = sigm(a3 + bso);
      cstate = gf * cstate + gi * gc;
      float hv = go * tanh_c(cstate);
      hnext[(size_t)b * HH + u] = hv;
    } else {
      // ---- final outputs: h and c (after step TT-1; state in hprev) ----
      out[(size_t)(BB * TT * OO) + (size_t)b * HH + u] = hprev[(size_t)b * HH + u];
      out[(size_t)(BB * TT * OO + BB * HH) + (size_t)b * HH + u] = cstate;
    }

    if (it < TT) grid_barrier(bar, 256u * (uint32_t)(it + 1));
  }
}

extern "C" void kernel_launch(void* const* d_in, const int* in_sizes, int n_in,
                              void* d_out, int out_size, void* d_ws, size_t ws_size,
                              hipStream_t stream) {
  (void)in_sizes; (void)n_in; (void)out_size; (void)ws_size;
  const float* x   = (const float*)d_in[0];
  const float* Wf  = (const float*)d_in[1];
  const float* bf  = (const float*)d_in[2];
  const float* Wi  = (const float*)d_in[3];
  const float* bi  = (const float*)d_in[4];
  const float* Wc  = (const float*)d_in[5];
  const float* bc  = (const float*)d_in[6];
  const float* Wo  = (const float*)d_in[7];
  const float* bo  = (const float*)d_in[8];
  const float* Wfc = (const float*)d_in[9];
  const float* bfc = (const float*)d_in[10];
  float* out = (float*)d_out;
  float* ws  = (float*)d_ws;

  // zero barrier counter + h0 (deterministic per call; ws is NOT re-poisoned)
  hipMemsetAsync(d_ws, 0, (size_t)WS_NFLOATS * sizeof(float), stream);

  hipFuncSetAttribute((const void*)lstm_kernel,
                      hipFuncAttributeMaxDynamicSharedMemorySize,
                      (int)(L_NFLOATS * sizeof(float)));

  void* args[] = { &x, &Wf, &bf, &Wi, &bi, &Wc, &bc, &Wo, &bo, &Wfc, &bfc, &out, &ws };
  hipLaunchCooperativeKernel(reinterpret_cast<void*>(lstm_kernel),
                             dim3(NBLK), dim3(NTHR), args,
                             (unsigned)(L_NFLOATS * sizeof(float)), stream);
}

// Round 2
// 60447.668 us; speedup vs baseline: 1.3742x; 1.3742x over previous
//
#include <hip/hip_runtime.h>
#include <stdint.h>

#define BB 64
#define TT 512
#define II 512
#define HH 1024
#define OO 512
#define KD 1536      // II + HH
#define KC 256       // k-chunk staged in LDS
#define NCH 6        // KD / KC
#define NBLK 256
#define NTHR 512
#define NWAVE 8

// workspace layout (floats)
#define WS_HBUF 256                       // [2][BB][HH] h double buffer
#define WS_NFLOATS (WS_HBUF + 2 * BB * HH)

// LDS layout (floats)
#define L_COMB0 0
#define L_COMB1 (KC * BB)                 // 16384
#define L_YBUF  (2 * KC * BB)             // 32768
#define L_GPART (L_YBUF + NWAVE * BB)     // 33280
#define L_NFLOATS (L_GPART + NWAVE * 4 * BB)  // 35328 floats = 141312 B

__device__ __forceinline__ float sigm(float v) {
  return 1.0f / (1.0f + __expf(-v));
}
__device__ __forceinline__ float tanh_c(float v) {
  v = fminf(fmaxf(v, -20.0f), 20.0f);
  float e = __expf(-2.0f * v);
  return (1.0f - e) / (1.0f + e);
}

// Grid barrier: relaxed spin (NO acquire in the poll loop — acquire at agent
// scope emits buffer_inv, and polling with it invalidates the XCD's L2
// continuously, evicting the L2-resident weights; that was round-1's 20x).
__device__ __forceinline__ void grid_barrier(uint32_t* cnt, uint32_t target) {
  asm volatile("s_waitcnt vmcnt(0) lgkmcnt(0)" ::: "memory");
  __syncthreads();
  if (threadIdx.x == 0) {
    __builtin_amdgcn_fence(__ATOMIC_RELEASE, "agent");   // waitcnt + wbl2 once
    __hip_atomic_fetch_add(cnt, 1u, __ATOMIC_RELAXED, __HIP_MEMORY_SCOPE_AGENT);
    while (__hip_atomic_load(cnt, __ATOMIC_RELAXED, __HIP_MEMORY_SCOPE_AGENT) < target) {
      __builtin_amdgcn_s_sleep(4);
    }
    __builtin_amdgcn_fence(__ATOMIC_ACQUIRE, "agent");   // one buffer_inv/step
  }
  __syncthreads();
}

__global__ void __launch_bounds__(NTHR, 2)
lstm_kernel(const float* __restrict__ x,
            const float* __restrict__ Wf, const float* __restrict__ bf,
            const float* __restrict__ Wi, const float* __restrict__ bi,
            const float* __restrict__ Wc, const float* __restrict__ bc,
            const float* __restrict__ Wo, const float* __restrict__ bo,
            const float* __restrict__ Wfc, const float* __restrict__ bfc,
            float* __restrict__ out, float* __restrict__ ws)
{
  extern __shared__ float lds[];
  const int tid  = threadIdx.x;
  const int blk  = blockIdx.x;
  const int wave = tid >> 6;
  const int lane = tid & 63;
  const int b    = lane;           // batch owned by this lane

  uint32_t* bar = (uint32_t*)ws;
  float* hbuf = ws + WS_HBUF;      // [2][BB][HH]

  // gate work: wave -> (hidden unit, k-half)
  const int ul = wave & 3;         // unit within block
  const int ks = wave >> 2;        // k-half (0/1): s in [ks*32, ks*32+32) per chunk
  const int u  = __builtin_amdgcn_readfirstlane(blk * 4 + ul);
  const float* rowf = Wf + (size_t)u * KD;
  const float* rowi = Wi + (size_t)u * KD;
  const float* rowc = Wc + (size_t)u * KD;
  const float* rowo = Wo + (size_t)u * KD;
  const float bsf = bf[u], bsi = bi[u], bsc = bc[u], bso = bo[u];

  // y work: wave -> (output col, k-quarter)
  const int ycol = wave >> 2;      // 0/1
  const int kq   = wave & 3;       // quarter of HH (256 floats)
  const int oidx = __builtin_amdgcn_readfirstlane(blk * 2 + ycol);
  const float* rowy = Wfc + (size_t)oidx * HH + kq * 256;

  float cstate = 0.0f;             // c[u][b] lives here (valid for waves 0-3)

  for (int it = 0; it <= TT; ++it) {
    const float* hprev = hbuf + (size_t)(it & 1) * (BB * HH);
    float*       hnext = hbuf + (size_t)((it + 1) & 1) * (BB * HH);

    // ---------- y_{it-1} = h_{it-1} @ Wfc^T + bfc (reads hprev) ----------
    if (it > 0) {
      float accy = 0.0f;
      const float* hrow = hprev + (size_t)b * HH + kq * 256;
      #pragma unroll 4
      for (int s = 0; s < 64; ++s) {
        float4 hv = ((const float4*)hrow)[s];
        float4 wv = ((const float4*)rowy)[s];
        accy += hv.x * wv.x + hv.y * wv.y + hv.z * wv.z + hv.w * wv.w;
      }
      lds[L_YBUF + wave * BB + b] = accy;
      __syncthreads();
      if (tid < 2 * BB) {
        int q  = tid >> 6;
        int qb = tid & 63;
        float yv = lds[L_YBUF + (q * 4 + 0) * BB + qb]
                 + lds[L_YBUF + (q * 4 + 1) * BB + qb]
                 + lds[L_YBUF + (q * 4 + 2) * BB + qb]
                 + lds[L_YBUF + (q * 4 + 3) * BB + qb]
                 + bfc[blk * 2 + q];
        out[(size_t)qb * (TT * OO) + (size_t)(it - 1) * OO + (blk * 2 + q)] = yv;
      }
    }

    if (it < TT) {
      float a0 = 0.f, a1 = 0.f, a2 = 0.f, a3 = 0.f;

      // ---- prologue: stage chunk 0 (pure x) linear-src -> swizzled LDS ----
      {
        float4 v[8];
        #pragma unroll
        for (int i = 0; i < 8; ++i) {
          int bs = i * 8 + wave;
          const float* src = x + (size_t)bs * (TT * II) + (size_t)it * II;
          v[i] = ((const float4*)src)[lane];
        }
        float4* dstb = (float4*)(lds + L_COMB0);
        #pragma unroll
        for (int i = 0; i < 8; ++i) {
          int bs = i * 8 + wave;
          dstb[bs * 64 + (lane ^ (bs & 15))] = v[i];
        }
      }
      __syncthreads();

      // ---- main K loop: double-buffered chunks; each wave does its s-half ----
      const int s0 = ks * 32;
      for (int kc = 0; kc < NCH; ++kc) {
        float4 v[8];
        if (kc + 1 < NCH) {                      // issue next chunk's loads
          const int k0n = (kc + 1) * KC;
          #pragma unroll
          for (int i = 0; i < 8; ++i) {
            int bs = i * 8 + wave;
            const float* src = (k0n < II)
              ? (x + (size_t)bs * (TT * II) + (size_t)it * II + k0n)
              : (hprev + (size_t)bs * HH + (k0n - II));
            v[i] = ((const float4*)src)[lane];
          }
        }
        {
          const float4* cb = (const float4*)(lds + ((kc & 1) ? L_COMB1 : L_COMB0)) + b * 64;
          const int k0 = kc * KC;
          const int m = b & 15;
          #pragma unroll 4
          for (int s = s0; s < s0 + 32; ++s) {
            float4 cv = cb[s ^ m];
            float4 w0 = *(const float4*)(rowf + k0 + 4 * s);
            float4 w1 = *(const float4*)(rowi + k0 + 4 * s);
            float4 w2 = *(const float4*)(rowc + k0 + 4 * s);
            float4 w3 = *(const float4*)(rowo + k0 + 4 * s);
            a0 += cv.x * w0.x + cv.y * w0.y + cv.z * w0.z + cv.w * w0.w;
            a1 += cv.x * w1.x + cv.y * w1.y + cv.z * w1.z + cv.w * w1.w;
            a2 += cv.x * w2.x + cv.y * w2.y + cv.z * w2.z + cv.w * w2.w;
            a3 += cv.x * w3.x + cv.y * w3.y + cv.z * w3.z + cv.w * w3.w;
          }
        }
        if (kc + 1 < NCH) {                      // write staged regs, swap
          float4* dstb = (float4*)(lds + (((kc + 1) & 1) ? L_COMB1 : L_COMB0));
          #pragma unroll
          for (int i = 0; i < 8; ++i) {
            int bs = i * 8 + wave;
            dstb[bs * 64 + (lane ^ (bs & 15))] = v[i];
          }
          __syncthreads();
        }
      }

      // ---- combine k-halves, elementwise update: c,h for (u, b) ----
      lds[L_GPART + wave * 256 + 0 * 64 + b] = a0;
      lds[L_GPART + wave * 256 + 1 * 64 + b] = a1;
      lds[L_GPART + wave * 256 + 2 * 64 + b] = a2;
      lds[L_GPART + wave * 256 + 3 * 64 + b] = a3;
      __syncthreads();
      if (wave < 4) {
        float t0 = lds[L_GPART + wave * 256 + 0 * 64 + b] + lds[L_GPART + (wave + 4) * 256 + 0 * 64 + b];
        float t1 = lds[L_GPART + wave * 256 + 1 * 64 + b] + lds[L_GPART + (wave + 4) * 256 + 1 * 64 + b];
        float t2 = lds[L_GPART + wave * 256 + 2 * 64 + b] + lds[L_GPART + (wave + 4) * 256 + 2 * 64 + b];
        float t3 = lds[L_GPART + wave * 256 + 3 * 64 + b] + lds[L_GPART + (wave + 4) * 256 + 3 * 64 + b];
        float gf = sigm(t0 + bsf);
        float gi = sigm(t1 + bsi);
        float gc = tanh_c(t2 + bsc);
        float go = sigm(t3 + bso);
        cstate = gf * cstate + gi * gc;
        float hv = go * tanh_c(cstate);
        hnext[(size_t)b * HH + u] = hv;
      }
    } else {
      // ---- final outputs: h and c (state after step TT-1 lives in hprev) ----
      if (wave < 4) {
        out[(size_t)(BB * TT * OO) + (size_t)b * HH + u] = hprev[(size_t)b * HH + u];
        out[(size_t)(BB * TT * OO + BB * HH) + (size_t)b * HH + u] = cstate;
      }
    }

    if (it < TT) grid_barrier(bar, 256u * (uint32_t)(it + 1));
  }
}

extern "C" void kernel_launch(void* const* d_in, const int* in_sizes, int n_in,
                              void* d_out, int out_size, void* d_ws, size_t ws_size,
                              hipStream_t stream) {
  (void)in_sizes; (void)n_in; (void)out_size; (void)ws_size;
  const float* x   = (const float*)d_in[0];
  const float* Wf  = (const float*)d_in[1];
  const float* bf  = (const float*)d_in[2];
  const float* Wi  = (const float*)d_in[3];
  const float* bi  = (const float*)d_in[4];
  const float* Wc  = (const float*)d_in[5];
  const float* bc  = (const float*)d_in[6];
  const float* Wo  = (const float*)d_in[7];
  const float* bo  = (const float*)d_in[8];
  const float* Wfc = (const float*)d_in[9];
  const float* bfc = (const float*)d_in[10];
  float* out = (float*)d_out;
  float* ws  = (float*)d_ws;

  // zero barrier counter + h0 (deterministic per call; ws is NOT re-poisoned)
  hipMemsetAsync(d_ws, 0, (size_t)WS_NFLOATS * sizeof(float), stream);

  hipFuncSetAttribute((const void*)lstm_kernel,
                      hipFuncAttributeMaxDynamicSharedMemorySize,
                      (int)(L_NFLOATS * sizeof(float)));

  void* args[] = { &x, &Wf, &bf, &Wi, &bi, &Wc, &bc, &Wo, &bo, &Wfc, &bfc, &out, &ws };
  hipLaunchCooperativeKernel(reinterpret_cast<void*>(lstm_kernel),
                             dim3(NBLK), dim3(NTHR), args,
                             (unsigned)(L_NFLOATS * sizeof(float)), stream);
}